// Round 1
// baseline (303.622 us; speedup 1.0000x reference)
//
#include <hip/hip_runtime.h>

#define IDIM 128
#define NS 256
#define NR 2048

__global__ __launch_bounds__(256)
void rf_kernel(const float* __restrict__ x, const float* __restrict__ dvec,
               const float* __restrict__ tmin, const float* __restrict__ tmax,
               const float* __restrict__ u, const float* __restrict__ grid,
               const float* __restrict__ opacity, float* __restrict__ out)
{
    const int ray = blockIdx.x;
    const int t = threadIdx.x;

    __shared__ float s_samp[NS];
    __shared__ float s_scan[NS];
    __shared__ float s_red[4][3];

    // ray data (broadcast loads, L1-cached)
    const float ox = x[ray*3+0], oy = x[ray*3+1], oz = x[ray*3+2];
    const float dx = dvec[ray*3+0], dy = dvec[ray*3+1], dz = dvec[ray*3+2];
    const float t0 = tmin[ray], t1 = tmax[ray];

    // stratified sample for this thread
    float samp = (t1 - t0) * u[ray*NS + t] + t0;
    s_samp[t] = samp;
    __syncthreads();

    // bitonic sort ascending (256 elements, one per thread)
    for (int k = 2; k <= NS; k <<= 1) {
        for (int j = k >> 1; j > 0; j >>= 1) {
            int ixj = t ^ j;
            if (ixj > t) {
                float a = s_samp[t], b = s_samp[ixj];
                bool up = ((t & k) == 0);
                if ((a > b) == up) { s_samp[t] = b; s_samp[ixj] = a; }
            }
            __syncthreads();
        }
    }

    samp = s_samp[t];
    float samp_next = (t < NS-1) ? s_samp[t+1] : samp;

    // SH basis of (re)normalized direction, scaled by K_SH
    const float rn = rsqrtf(dx*dx + dy*dy + dz*dz);
    const float sx = dx*rn, sy = dy*rn, sz = dz*rn;
    float sh[9];
    sh[0] = 0.28209479f;
    sh[1] = 0.48860251f * sy;
    sh[2] = 0.48860251f * sz;
    sh[3] = 0.48860251f * sx;
    sh[4] = 1.09254843f * sx*sy;
    sh[5] = 1.09254843f * sy*sz;
    sh[6] = 0.31539157f * (3.0f*sz*sz - 1.0f);
    sh[7] = 1.09254843f * sx*sz;
    sh[8] = 0.54627422f * (sx*sx - sy*sy);

    // sample point, enclosing cell, fractional coords
    const float px = ox + samp*dx, py = oy + samp*dy, pz = oz + samp*dz;
    int ci = min(max((int)floorf(px), 0), IDIM-2);
    int cj = min(max((int)floorf(py), 0), IDIM-2);
    int ck = min(max((int)floorf(pz), 0), IDIM-2);
    const float fx = px - (float)ci, fy = py - (float)cj, fz = pz - (float)ck;

    // trilinear gather: 8 corners x (27 SH coeffs + opacity)
    float c0 = 0.f, c1 = 0.f, c2 = 0.f, op = 0.f;
    #pragma unroll
    for (int e = 0; e < 8; ++e) {
        const int di = e & 1, dj = (e >> 1) & 1, dk = (e >> 2) & 1;
        const float w = (di ? fx : 1.f - fx) * (dj ? fy : 1.f - fy) * (dk ? fz : 1.f - fz);
        const int gi = ((ci + di) * IDIM + (cj + dj)) * IDIM + (ck + dk);
        const float* __restrict__ g = grid + (long)gi * 27;
        float d0 = 0.f, d1 = 0.f, d2 = 0.f;
        #pragma unroll
        for (int q = 0; q < 9; ++q) {
            d0 += sh[q] * g[q];
            d1 += sh[q] * g[9 + q];
            d2 += sh[q] * g[18 + q];
        }
        c0 += w * d0; c1 += w * d1; c2 += w * d2;
        op += w * opacity[gi];
    }
    c0 = fmaxf(c0 + 0.5f, 0.f);
    c1 = fmaxf(c1 + 0.5f, 0.f);
    c2 = fmaxf(c2 + 0.5f, 0.f);

    // dts_t = (s_{t+1} - s_t) * opacity_t for t < S-1
    const float dts = (t < NS-1) ? (samp_next - samp) * op : 0.f;

    // inclusive Hillis-Steele scan in LDS, then exclusive
    s_scan[t] = dts;
    __syncthreads();
    for (int off = 1; off < NS; off <<= 1) {
        float v = (t >= off) ? s_scan[t - off] : 0.f;
        __syncthreads();
        s_scan[t] += v;
        __syncthreads();
    }
    const float cum = s_scan[t] - dts;   // exclusive prefix

    const float wgt = (t < NS-1) ? expf(-cum) * (1.f - expf(-dts)) : 0.f;
    float r0 = wgt * c0, r1 = wgt * c1, r2 = wgt * c2;

    // block reduction: wave64 shuffle then 4-wave LDS combine
    #pragma unroll
    for (int off = 32; off > 0; off >>= 1) {
        r0 += __shfl_down(r0, off);
        r1 += __shfl_down(r1, off);
        r2 += __shfl_down(r2, off);
    }
    const int lane = t & 63, wv = t >> 6;
    if (lane == 0) { s_red[wv][0] = r0; s_red[wv][1] = r1; s_red[wv][2] = r2; }
    __syncthreads();
    if (t == 0) {
        out[ray*3+0] = s_red[0][0] + s_red[1][0] + s_red[2][0] + s_red[3][0];
        out[ray*3+1] = s_red[0][1] + s_red[1][1] + s_red[2][1] + s_red[3][1];
        out[ray*3+2] = s_red[0][2] + s_red[1][2] + s_red[2][2] + s_red[3][2];
    }
}

extern "C" void kernel_launch(void* const* d_in, const int* in_sizes, int n_in,
                              void* d_out, int out_size, void* d_ws, size_t ws_size,
                              hipStream_t stream) {
    const float* x       = (const float*)d_in[0];
    const float* d       = (const float*)d_in[1];
    const float* tmin    = (const float*)d_in[2];
    const float* tmax    = (const float*)d_in[3];
    const float* u       = (const float*)d_in[4];
    const float* grid    = (const float*)d_in[5];
    const float* opacity = (const float*)d_in[6];
    float* out = (float*)d_out;
    rf_kernel<<<NR, NS, 0, stream>>>(x, d, tmin, tmax, u, grid, opacity, out);
}

// Round 3
// 283.946 us; speedup vs baseline: 1.0693x; 1.0693x over previous
//
#include <hip/hip_runtime.h>

#define IDIM 128
#define NS 256
#define NR 2048
#define SLOTS 64

__global__ __launch_bounds__(256)
void rf_kernel(const float* __restrict__ x, const float* __restrict__ dvec,
               const float* __restrict__ tmin, const float* __restrict__ tmax,
               const float* __restrict__ u, const float* __restrict__ grid,
               const float* __restrict__ opacity, float* __restrict__ out)
{
    const int ray = blockIdx.x;
    const int t = threadIdx.x;
    const int lane = t & 63, wv = t >> 6;

    __shared__ float  s_samp[NS];
    __shared__ int    s_key[NS];
    __shared__ int    s_slotkey[SLOTS];
    __shared__ int    s_wsum[4];
    __shared__ float  s_wred[4];
    __shared__ float4 s_corner[SLOTS][9];   // [e]=0..7 used; stride 9 breaks 128B bank aliasing
    __shared__ float  s_red[4][3];

    // ray data (broadcast loads)
    const float ox = x[ray*3+0], oy = x[ray*3+1], oz = x[ray*3+2];
    const float dx = dvec[ray*3+0], dy = dvec[ray*3+1], dz = dvec[ray*3+2];
    const float t0 = tmin[ray], t1 = tmax[ray];

    // stratified sample for this thread
    float samp = (t1 - t0) * u[ray*NS + t] + t0;
    s_samp[t] = samp;
    __syncthreads();

    // bitonic sort ascending (256 elements, one per thread)
    for (int k = 2; k <= NS; k <<= 1) {
        for (int j = k >> 1; j > 0; j >>= 1) {
            int ixj = t ^ j;
            if (ixj > t) {
                float a = s_samp[t], b = s_samp[ixj];
                bool up = ((t & k) == 0);
                if ((a > b) == up) { s_samp[t] = b; s_samp[ixj] = a; }
            }
            __syncthreads();
        }
    }

    samp = s_samp[t];
    const float samp_next = (t < NS-1) ? s_samp[t+1] : samp;

    // SH basis of renormalized direction, scaled by K_SH (per-ray uniform)
    const float rn = rsqrtf(dx*dx + dy*dy + dz*dz);
    const float sx = dx*rn, sy = dy*rn, sz = dz*rn;
    float sh[9];
    sh[0] = 0.28209479f;
    sh[1] = 0.48860251f * sy;
    sh[2] = 0.48860251f * sz;
    sh[3] = 0.48860251f * sx;
    sh[4] = 1.09254843f * sx*sy;
    sh[5] = 1.09254843f * sy*sz;
    sh[6] = 0.31539157f * (3.0f*sz*sz - 1.0f);
    sh[7] = 1.09254843f * sx*sz;
    sh[8] = 0.54627422f * (sx*sx - sy*sy);

    // sample point, enclosing cell, fractional coords
    const float px = ox + samp*dx, py = oy + samp*dy, pz = oz + samp*dz;
    const int ci = min(max((int)floorf(px), 0), IDIM-2);
    const int cj = min(max((int)floorf(py), 0), IDIM-2);
    const int ck = min(max((int)floorf(pz), 0), IDIM-2);
    const float fx = px - (float)ci, fy = py - (float)cj, fz = pz - (float)ck;

    // ---- unique-cell detection (sorted samples -> contiguous runs) ----
    const int key = (ci << 14) | (cj << 7) | ck;
    s_key[t] = key;
    __syncthreads();
    const bool leader = (t == 0) || (s_key[t-1] != key);
    const unsigned long long m = __ballot(leader);
    const int incl = __popcll(m & (~0ull >> (63 - lane)));   // leaders <= me in wave
    if (lane == 63) s_wsum[wv] = __popcll(m);
    __syncthreads();
    int base = 0;
    #pragma unroll
    for (int w = 0; w < 4; ++w) base += (w < wv) ? s_wsum[w] : 0;
    const int slot = base + incl - 1;   // my cell's slot id
    const int U = s_wsum[0] + s_wsum[1] + s_wsum[2] + s_wsum[3];
    if (leader && slot < SLOTS) s_slotkey[slot] = key;
    __syncthreads();

    // ---- cooperative corner gather: U*8 tasks over 256 threads ----
    const int Ucap = (U < SLOTS ? U : SLOTS);
    for (int task = t; task < Ucap * 8; task += NS) {
        const int sl = task >> 3, e = task & 7;
        const int k2 = s_slotkey[sl];
        const int bi = (k2 >> 14) + (e & 1);
        const int bj = ((k2 >> 7) & 127) + ((e >> 1) & 1);
        const int bk = (k2 & 127) + ((e >> 2) & 1);
        const int gi = (bi * IDIM + bj) * IDIM + bk;
        const float* __restrict__ g = grid + (long)gi * 27;
        float d0 = 0.f, d1 = 0.f, d2 = 0.f;
        #pragma unroll
        for (int q = 0; q < 9; ++q) {
            d0 += sh[q] * g[q];
            d1 += sh[q] * g[9 + q];
            d2 += sh[q] * g[18 + q];
        }
        s_corner[sl][e] = make_float4(d0, d1, d2, opacity[gi]);
    }
    __syncthreads();

    // ---- per-sample trilinear combine from LDS ----
    float c0, c1, c2, op;
    if (slot < SLOTS) {
        c0 = c1 = c2 = op = 0.f;
        #pragma unroll
        for (int e = 0; e < 8; ++e) {
            const float w = ((e & 1) ? fx : 1.f - fx)
                          * (((e >> 1) & 1) ? fy : 1.f - fy)
                          * (((e >> 2) & 1) ? fz : 1.f - fz);
            const float4 v = s_corner[slot][e];
            c0 += w * v.x; c1 += w * v.y; c2 += w * v.z; op += w * v.w;
        }
    } else {
        // overflow fallback (never expected: U <= ~29): direct gather
        c0 = c1 = c2 = op = 0.f;
        for (int e = 0; e < 8; ++e) {
            const float w = ((e & 1) ? fx : 1.f - fx)
                          * (((e >> 1) & 1) ? fy : 1.f - fy)
                          * (((e >> 2) & 1) ? fz : 1.f - fz);
            const int gi = ((ci + (e & 1)) * IDIM + (cj + ((e >> 1) & 1))) * IDIM
                         + (ck + ((e >> 2) & 1));
            const float* __restrict__ g = grid + (long)gi * 27;
            float d0 = 0.f, d1 = 0.f, d2 = 0.f;
            for (int q = 0; q < 9; ++q) {
                d0 += sh[q] * g[q];
                d1 += sh[q] * g[9 + q];
                d2 += sh[q] * g[18 + q];
            }
            c0 += w * d0; c1 += w * d1; c2 += w * d2;
            op += w * opacity[gi];
        }
    }
    c0 = fmaxf(c0 + 0.5f, 0.f);
    c1 = fmaxf(c1 + 0.5f, 0.f);
    c2 = fmaxf(c2 + 0.5f, 0.f);

    // dts_t = (s_{t+1} - s_t) * opacity_t for t < S-1
    const float dts = (t < NS-1) ? (samp_next - samp) * op : 0.f;

    // ---- exclusive prefix sum via wave shuffle scan (3 barriers total) ----
    float v = dts;
    #pragma unroll
    for (int off = 1; off < 64; off <<= 1) {
        const float n = __shfl_up(v, off);
        if (lane >= off) v += n;
    }
    if (lane == 63) s_wred[wv] = v;
    __syncthreads();
    float wbase = 0.f;
    #pragma unroll
    for (int w = 0; w < 4; ++w) wbase += (w < wv) ? s_wred[w] : 0.f;
    const float cum = (v + wbase) - dts;   // exclusive prefix

    const float wgt = (t < NS-1) ? expf(-cum) * (1.f - expf(-dts)) : 0.f;
    float r0 = wgt * c0, r1 = wgt * c1, r2 = wgt * c2;

    // block reduction: wave shuffle then 4-wave LDS combine
    #pragma unroll
    for (int off = 32; off > 0; off >>= 1) {
        r0 += __shfl_down(r0, off);
        r1 += __shfl_down(r1, off);
        r2 += __shfl_down(r2, off);
    }
    if (lane == 0) { s_red[wv][0] = r0; s_red[wv][1] = r1; s_red[wv][2] = r2; }
    __syncthreads();
    if (t == 0) {
        out[ray*3+0] = s_red[0][0] + s_red[1][0] + s_red[2][0] + s_red[3][0];
        out[ray*3+1] = s_red[0][1] + s_red[1][1] + s_red[2][1] + s_red[3][1];
        out[ray*3+2] = s_red[0][2] + s_red[1][2] + s_red[2][2] + s_red[3][2];
    }
}

extern "C" void kernel_launch(void* const* d_in, const int* in_sizes, int n_in,
                              void* d_out, int out_size, void* d_ws, size_t ws_size,
                              hipStream_t stream) {
    const float* x       = (const float*)d_in[0];
    const float* d       = (const float*)d_in[1];
    const float* tmin    = (const float*)d_in[2];
    const float* tmax    = (const float*)d_in[3];
    const float* u       = (const float*)d_in[4];
    const float* grid    = (const float*)d_in[5];
    const float* opacity = (const float*)d_in[6];
    float* out = (float*)d_out;
    rf_kernel<<<NR, NS, 0, stream>>>(x, d, tmin, tmax, u, grid, opacity, out);
}

// Round 6
// 280.152 us; speedup vs baseline: 1.0838x; 1.0135x over previous
//
#include <hip/hip_runtime.h>

#define IDIM 128
#define NS 256
#define NR 2048
#define SLOTS 64

__global__ __launch_bounds__(256)
void rf_kernel(const float* __restrict__ x, const float* __restrict__ dvec,
               const float* __restrict__ tmin, const float* __restrict__ tmax,
               const float* __restrict__ u, const float* __restrict__ grid,
               const float* __restrict__ opacity, float* __restrict__ out)
{
    const int ray = blockIdx.x;
    const int t = threadIdx.x;
    const int lane = t & 63, wv = t >> 6;

    __shared__ float  s_samp[NS];
    __shared__ int    s_key[NS];
    __shared__ int    s_slotkey[SLOTS];
    __shared__ int    s_wsum[4];
    __shared__ float  s_wred[4];
    __shared__ float4 s_corner[SLOTS][9];   // [e]=0..7 used; stride 9 breaks 128B bank aliasing
    __shared__ float  s_red[4][3];
    __shared__ float  s_first[4];           // lane-0 sorted value per wave (for samp_next handoff)

    // ray data (broadcast loads)
    const float ox = x[ray*3+0], oy = x[ray*3+1], oz = x[ray*3+2];
    const float dx = dvec[ray*3+0], dy = dvec[ray*3+1], dz = dvec[ray*3+2];
    const float t0 = tmin[ray], t1 = tmax[ray];

    // stratified sample for this thread
    float v = (t1 - t0) * u[ray*NS + t] + t0;

    // ---- bitonic sort, shuffle-based: barriers only for cross-wave stages ----
    // k = 2..64: all stages intra-wave (j <= 32)
    #pragma unroll
    for (int k = 2; k <= 64; k <<= 1) {
        #pragma unroll
        for (int j = k >> 1; j > 0; j >>= 1) {
            const float p = __shfl_xor(v, j);
            const bool up = ((t & k) == 0);
            const bool lower = ((t & j) == 0);
            v = (lower == up) ? fminf(v, p) : fmaxf(v, p);
        }
    }
    // k = 128: j=64 cross-wave via LDS, then j<=32 intra-wave
    {
        s_samp[t] = v; __syncthreads();
        const float p = s_samp[t ^ 64];
        const bool up = ((t & 128) == 0);
        v = (((t & 64) == 0) == up) ? fminf(v, p) : fmaxf(v, p);
        #pragma unroll
        for (int j = 32; j > 0; j >>= 1) {
            const float q = __shfl_xor(v, j);
            v = (((t & j) == 0) == up) ? fminf(v, q) : fmaxf(v, q);
        }
    }
    // k = 256 (up = true everywhere): j=128,64 cross-wave, then j<=32 intra-wave
    {
        __syncthreads();
        s_samp[t] = v; __syncthreads();
        float p = s_samp[t ^ 128];
        v = (((t & 128) == 0)) ? fminf(v, p) : fmaxf(v, p);
        __syncthreads();
        s_samp[t] = v; __syncthreads();
        p = s_samp[t ^ 64];
        v = (((t & 64) == 0)) ? fminf(v, p) : fmaxf(v, p);
        #pragma unroll
        for (int j = 32; j > 0; j >>= 1) {
            const float q = __shfl_xor(v, j);
            v = (((t & j) == 0)) ? fminf(v, q) : fmaxf(v, q);
        }
    }
    const float samp = v;
    // samp_next: shuffle within wave; cross-wave boundary via 4-float LDS handoff
    float samp_next = __shfl_down(samp, 1);
    if (lane == 0) s_first[wv] = samp;
    __syncthreads();
    if (lane == 63) samp_next = (wv < 3) ? s_first[wv + 1] : samp;

    // SH basis of renormalized direction, scaled by K_SH (per-ray uniform)
    const float rn = rsqrtf(dx*dx + dy*dy + dz*dz);
    const float sx = dx*rn, sy = dy*rn, sz = dz*rn;
    float sh[9];
    sh[0] = 0.28209479f;
    sh[1] = 0.48860251f * sy;
    sh[2] = 0.48860251f * sz;
    sh[3] = 0.48860251f * sx;
    sh[4] = 1.09254843f * sx*sy;
    sh[5] = 1.09254843f * sy*sz;
    sh[6] = 0.31539157f * (3.0f*sz*sz - 1.0f);
    sh[7] = 1.09254843f * sx*sz;
    sh[8] = 0.54627422f * (sx*sx - sy*sy);

    // sample point, enclosing cell, fractional coords
    const float px = ox + samp*dx, py = oy + samp*dy, pz = oz + samp*dz;
    const int ci = min(max((int)floorf(px), 0), IDIM-2);
    const int cj = min(max((int)floorf(py), 0), IDIM-2);
    const int ck = min(max((int)floorf(pz), 0), IDIM-2);
    const float fx = px - (float)ci, fy = py - (float)cj, fz = pz - (float)ck;

    // ---- unique-cell detection (sorted samples -> contiguous runs) ----
    const int key = (ci << 14) | (cj << 7) | ck;
    s_key[t] = key;
    __syncthreads();
    const bool leader = (t == 0) || (s_key[t-1] != key);
    const unsigned long long m = __ballot(leader);
    const int incl = __popcll(m & (~0ull >> (63 - lane)));   // leaders <= me in wave
    if (lane == 63) s_wsum[wv] = __popcll(m);
    __syncthreads();
    int base = 0;
    #pragma unroll
    for (int w = 0; w < 4; ++w) base += (w < wv) ? s_wsum[w] : 0;
    const int slot = base + incl - 1;   // my cell's slot id
    const int U = s_wsum[0] + s_wsum[1] + s_wsum[2] + s_wsum[3];
    if (leader && slot < SLOTS) s_slotkey[slot] = key;
    __syncthreads();

    // ---- cooperative corner gather: U*8 tasks over 256 threads ----
    const int Ucap = (U < SLOTS ? U : SLOTS);
    for (int task = t; task < Ucap * 8; task += NS) {
        const int sl = task >> 3, e = task & 7;
        const int k2 = s_slotkey[sl];
        const int bi = (k2 >> 14) + (e & 1);
        const int bj = ((k2 >> 7) & 127) + ((e >> 1) & 1);
        const int bk = (k2 & 127) + ((e >> 2) & 1);
        const int gi = (bi * IDIM + bj) * IDIM + bk;
        const float* __restrict__ g = grid + (long)gi * 27;
        float d0 = 0.f, d1 = 0.f, d2 = 0.f;
        #pragma unroll
        for (int q = 0; q < 9; ++q) {
            d0 += sh[q] * g[q];
            d1 += sh[q] * g[9 + q];
            d2 += sh[q] * g[18 + q];
        }
        s_corner[sl][e] = make_float4(d0, d1, d2, opacity[gi]);
    }
    __syncthreads();

    // ---- per-sample trilinear combine from LDS ----
    float c0, c1, c2, op;
    if (slot < SLOTS) {
        c0 = c1 = c2 = op = 0.f;
        #pragma unroll
        for (int e = 0; e < 8; ++e) {
            const float w = ((e & 1) ? fx : 1.f - fx)
                          * (((e >> 1) & 1) ? fy : 1.f - fy)
                          * (((e >> 2) & 1) ? fz : 1.f - fz);
            const float4 cv = s_corner[slot][e];
            c0 += w * cv.x; c1 += w * cv.y; c2 += w * cv.z; op += w * cv.w;
        }
    } else {
        // overflow fallback (never expected: U <= ~49): direct gather
        c0 = c1 = c2 = op = 0.f;
        for (int e = 0; e < 8; ++e) {
            const float w = ((e & 1) ? fx : 1.f - fx)
                          * (((e >> 1) & 1) ? fy : 1.f - fy)
                          * (((e >> 2) & 1) ? fz : 1.f - fz);
            const int gi = ((ci + (e & 1)) * IDIM + (cj + ((e >> 1) & 1))) * IDIM
                         + (ck + ((e >> 2) & 1));
            const float* __restrict__ g = grid + (long)gi * 27;
            float d0 = 0.f, d1 = 0.f, d2 = 0.f;
            for (int q = 0; q < 9; ++q) {
                d0 += sh[q] * g[q];
                d1 += sh[q] * g[9 + q];
                d2 += sh[q] * g[18 + q];
            }
            c0 += w * d0; c1 += w * d1; c2 += w * d2;
            op += w * opacity[gi];
        }
    }
    c0 = fmaxf(c0 + 0.5f, 0.f);
    c1 = fmaxf(c1 + 0.5f, 0.f);
    c2 = fmaxf(c2 + 0.5f, 0.f);

    // dts_t = (s_{t+1} - s_t) * opacity_t for t < S-1
    const float dts = (t < NS-1) ? (samp_next - samp) * op : 0.f;

    // ---- exclusive prefix sum via wave shuffle scan ----
    float pv = dts;
    #pragma unroll
    for (int off = 1; off < 64; off <<= 1) {
        const float n = __shfl_up(pv, off);
        if (lane >= off) pv += n;
    }
    if (lane == 63) s_wred[wv] = pv;
    __syncthreads();
    float wbase = 0.f;
    #pragma unroll
    for (int w = 0; w < 4; ++w) wbase += (w < wv) ? s_wred[w] : 0.f;
    const float cum = (pv + wbase) - dts;   // exclusive prefix

    const float wgt = (t < NS-1) ? __expf(-cum) * (1.f - __expf(-dts)) : 0.f;
    float r0 = wgt * c0, r1 = wgt * c1, r2 = wgt * c2;

    // block reduction: wave shuffle then 4-wave LDS combine
    #pragma unroll
    for (int off = 32; off > 0; off >>= 1) {
        r0 += __shfl_down(r0, off);
        r1 += __shfl_down(r1, off);
        r2 += __shfl_down(r2, off);
    }
    if (lane == 0) { s_red[wv][0] = r0; s_red[wv][1] = r1; s_red[wv][2] = r2; }
    __syncthreads();
    if (t == 0) {
        out[ray*3+0] = s_red[0][0] + s_red[1][0] + s_red[2][0] + s_red[3][0];
        out[ray*3+1] = s_red[0][1] + s_red[1][1] + s_red[2][1] + s_red[3][1];
        out[ray*3+2] = s_red[0][2] + s_red[1][2] + s_red[2][2] + s_red[3][2];
    }
}

extern "C" void kernel_launch(void* const* d_in, const int* in_sizes, int n_in,
                              void* d_out, int out_size, void* d_ws, size_t ws_size,
                              hipStream_t stream) {
    const float* x       = (const float*)d_in[0];
    const float* d       = (const float*)d_in[1];
    const float* tmin    = (const float*)d_in[2];
    const float* tmax    = (const float*)d_in[3];
    const float* u       = (const float*)d_in[4];
    const float* grid    = (const float*)d_in[5];
    const float* opacity = (const float*)d_in[6];
    float* out = (float*)d_out;
    rf_kernel<<<NR, NS, 0, stream>>>(x, d, tmin, tmax, u, grid, opacity, out);
}